// Round 19
// baseline (474.224 us; speedup 1.0000x reference)
//
#include <hip/hip_runtime.h>
#include <stdint.h>
#include <math.h>

#define NN 10000
#define NE 30000
#define NG 50
#define NH 8

typedef _Float16 f16;
typedef _Float16 f16x2 __attribute__((ext_vector_type(2)));
typedef _Float16 f16x4 __attribute__((ext_vector_type(4)));
typedef _Float16 f16x8 __attribute__((ext_vector_type(8)));
typedef float f32x4 __attribute__((ext_vector_type(4)));

// ---------------- helpers ----------------
__device__ inline void async16(f16* l, const f16* g) {
    __builtin_amdgcn_global_load_lds((const __attribute__((address_space(1))) void*)g,
                                     (__attribute__((address_space(3))) void*)l, 16, 0, 0);
}

// ---------------- CSR build (parallel multi-kernel; R15-proven) ----------------
__global__ void hist_kernel(const int* __restrict__ dst, int* __restrict__ deg, int E) {
    int e = blockIdx.x * blockDim.x + threadIdx.x;
    if (e < E) atomicAdd(&deg[dst[e]], 1);
}

__global__ __launch_bounds__(1024) void scan_goffs(const int* __restrict__ deg, int* __restrict__ offs,
                                                   int* __restrict__ cursor,
                                                   const int* __restrict__ batch, int* __restrict__ goffs) {
    if (blockIdx.x == 1) {
        int g = threadIdx.x;
        if (g > NG) return;
        int lo = 0, hi = NN;
        while (lo < hi) {
            int mid = (lo + hi) >> 1;
            if (batch[mid] < g) lo = mid + 1; else hi = mid;
        }
        goffs[g] = lo;
        return;
    }
    __shared__ int tot[1024];
    const int t = threadIdx.x;
    const int base = t * 10;
    int v[10];
    int s = 0;
#pragma unroll
    for (int i = 0; i < 10; ++i) {
        int idx = base + i;
        v[i] = (idx < NN) ? deg[idx] : 0;
        s += v[i];
    }
    tot[t] = s;
    __syncthreads();
    for (int d2 = 1; d2 < 1024; d2 <<= 1) {
        int add = (t >= d2) ? tot[t - d2] : 0;
        __syncthreads();
        tot[t] += add;
        __syncthreads();
    }
    int run = tot[t] - s;
    if (t == 0) offs[0] = 0;
#pragma unroll
    for (int i = 0; i < 10; ++i) {
        int idx = base + i;
        if (idx < NN) cursor[idx] = run;
        run += v[i];
        if (idx < NN) offs[idx + 1] = run;
    }
}

__global__ void scatter_kernel(const int* __restrict__ src, const int* __restrict__ dst,
                               int* __restrict__ cursor, int* __restrict__ srcCSR, int E) {
    int e = blockIdx.x * blockDim.x + threadIdx.x;
    if (e < E) {
        int p = atomicAdd(&cursor[dst[e]], 1);
        srcCSR[p] = src[e];
    }
}

// per-segment insertion sort -> deterministic CSR (fixed fp32 summation orders)
__global__ void sort_csr(const int* __restrict__ offs, int* __restrict__ srcCSR) {
    int n = blockIdx.x * blockDim.x + threadIdx.x;
    if (n >= NN) return;
    int s = offs[n], e = offs[n + 1];
    for (int i = s + 1; i < e; ++i) {
        int v = srcCSR[i];
        int j = i - 1;
        while (j >= s && srcCSR[j] > v) { srcCSR[j + 1] = srcCSR[j]; --j; }
        srcCSR[j + 1] = v;
    }
}

// ---------------- megaprep: all conversions + weight preps + zero-init, ONE dispatch --
#define MB_CVTX   0
#define MB_CVTQ   5000
#define MB_CVTK   7048
#define MB_P4L2   9096
#define MB_P4L3   9896
#define MB_PZB    10000
#define MB_PU     10296
#define MB_ZERO   10808
#define MB_TOTAL  10854

__device__ void prep4_tile(const float* __restrict__ W0, int n0, const float* __restrict__ W1, int n1,
                           const float* __restrict__ W2, int n2, const float* __restrict__ W3, int n3,
                           const float* __restrict__ b0, const float* __restrict__ b1,
                           const float* __restrict__ b2, const float* __restrict__ b3,
                           f16* __restrict__ Bt, float* __restrict__ bias, int K, int bx, int by) {
    __shared__ float tile[64][65];
    const int k0 = bx * 64;
    const int nb = by * 64;
    const int tid = threadIdx.x;
    const int tn = tid & 63;
    const int t4 = tid >> 6;
#pragma unroll
    for (int i = 0; i < 16; ++i) {
        int kl = t4 + i * 4;
        int k = k0 + kl;
        int n = nb + tn;
        float w = 0.0f;
        int m = n;
        if (m < n0) w = W0[(size_t)k * n0 + m];
        else { m -= n0;
            if (m < n1) w = W1[(size_t)k * n1 + m];
            else { m -= n1;
                if (m < n2) w = W2[(size_t)k * n2 + m];
                else { m -= n2; if (m < n3) w = W3[(size_t)k * n3 + m]; }
            }
        }
        tile[kl][tn] = w;
    }
    if (bx == 0 && t4 == 0) {
        int n = nb + tn;
        float bv = 0.0f;
        int m = n;
        if (m < n0) bv = b0[m];
        else { m -= n0;
            if (m < n1) bv = b1[m];
            else { m -= n1;
                if (m < n2) bv = b2[m];
                else { m -= n2; if (m < n3) bv = b3[m]; }
            }
        }
        bias[n] = bv;
    }
    __syncthreads();
#pragma unroll
    for (int i = 0; i < 16; ++i) {
        int nl = t4 + i * 4;
        Bt[(size_t)(nb + nl) * K + k0 + tn] = (f16)tile[tn][nl];
    }
}

__global__ __launch_bounds__(256) void megaprep(
        const float* __restrict__ x, f16* __restrict__ xh,
        const float* __restrict__ qw1, f16* __restrict__ qw16,
        const float* __restrict__ kw1, f16* __restrict__ kw16,
        const float* __restrict__ qb1, const float* __restrict__ kb1,
        const float* __restrict__ vw1, const float* __restrict__ sw1,
        const float* __restrict__ vb1, const float* __restrict__ sb1,
        const float* __restrict__ qw2, const float* __restrict__ qb2,
        const float* __restrict__ kw2, const float* __restrict__ kb2,
        const float* __restrict__ vw2, const float* __restrict__ vb2,
        const float* __restrict__ sw2, const float* __restrict__ sb2,
        const float* __restrict__ qw3, const float* __restrict__ qb3,
        const float* __restrict__ kw3, const float* __restrict__ kb3,
        const float* __restrict__ vw3, const float* __restrict__ vb3,
        const float* __restrict__ sw3, const float* __restrict__ sb3,
        f16* __restrict__ BtL2, float* __restrict__ biasL2,
        f16* __restrict__ BtL3, float* __restrict__ biasL3,
        f16* __restrict__ BtZ, float* __restrict__ biasZ,
        f16* __restrict__ BtY, float* __restrict__ biasY,
        float* __restrict__ zbias, int* __restrict__ deg) {
    const int b = blockIdx.x;
    const int tid = threadIdx.x;

    if (b < MB_CVTQ) {
        int i = b * 256 + tid;
        if (i < NN * 128) xh[i] = (f16)x[i];
    } else if (b < MB_CVTK) {
        int i = (b - MB_CVTQ) * 256 + tid;
        qw16[i] = (f16)qw1[i];
    } else if (b < MB_P4L2) {
        int i = (b - MB_CVTK) * 256 + tid;
        kw16[i] = (f16)kw1[i];
    } else if (b < MB_P4L3) {
        int r = b - MB_P4L2;
        prep4_tile(qw2, 2048, kw2, 2048, vw2, 2048, sw2, 256,
                   qb2, kb2, vb2, sb2, BtL2, biasL2, 512, r & 7, r >> 3);
    } else if (b < MB_PZB) {
        int r = b - MB_P4L3;
        prep4_tile(qw3, 512, kw3, 512, vw3, 512, sw3, 64,
                   qb3, kb3, vb3, sb3, BtL3, biasL3, 256, r & 3, r >> 2);
    } else if (b < MB_PU) {
        int r = b - MB_PZB;
        int bx = r % 37, by = r / 37;
        __shared__ f16 ztile[32][65];
        const int k0 = bx * 32, c0 = by * 64;
#pragma unroll
        for (int i = 0; i < 8; ++i) {
            int idx = tid + i * 256;
            int kl = idx >> 6, cl = idx & 63;
            int k = k0 + kl, c = c0 + cl;
            float v = 0.0f;
            if (k < 1024)      v = vw1[(size_t)(k & 127) * 4096 + (k >> 7) * 512 + c];
            else if (k < 1152) v = sw1[(size_t)(k - 1024) * 512 + c];
            else if (k < 1160) v = vb1[(k - 1152) * 512 + c];
            ztile[kl][cl] = (f16)v;
        }
        if (bx == 0 && tid < 64) biasZ[c0 + tid] = sb1[c0 + tid];
        __syncthreads();
        const int cl = tid >> 2, kl = (tid & 3) * 8;
        f16x8 v;
#pragma unroll
        for (int t2 = 0; t2 < 8; ++t2) v[t2] = ztile[kl + t2][cl];
        *(f16x8*)(BtZ + (size_t)(c0 + cl) * 1184 + k0 + kl) = v;
    } else if (b < MB_ZERO) {
        const int fin = 128, hc = 4096, C = 512;
        const int wid = (b - MB_PU) * 4 + (tid >> 6);
        const int lane = tid & 63;
        if (wid >= fin * 16) return;
        const int k = wid >> 4;
        const int idx = wid & 15;
        const int h = idx & 7, isV = idx >> 3;
        const float* W = isV ? kw1 : qw1;
        const float* bvec = isV ? qb1 : kb1;
        float s = 0.0f;
        for (int c = lane; c < C; c += 64) s += W[(size_t)k * hc + h * C + c] * bvec[h * C + c];
#pragma unroll
        for (int o = 32; o > 0; o >>= 1) s += __shfl_down(s, o, 64);
        if (lane == 0) BtY[(size_t)(8 * fin + isV * 8 + h) * fin + k] = (f16)s;
        if (wid < 8) {
            float cc = 0.0f;
            for (int c = lane; c < C; c += 64) cc += qb1[wid * C + c] * kb1[wid * C + c];
#pragma unroll
            for (int o = 32; o > 0; o >>= 1) cc += __shfl_down(cc, o, 64);
            if (lane == 0) biasY[8 * fin + wid] = cc;
        }
    } else {
        int idx = (b - MB_ZERO) * 256 + tid;
        if (idx < 512) zbias[idx] = 0.0f;
        else if (idx < 1536) biasY[idx - 512] = 0.0f;
        else if (idx < 1656) biasY[1032 + idx - 1536] = 0.0f;
        else if (idx < 1656 + NN) deg[idx - 1656] = 0;
    }
}

// ---------------- gemm128: 128x128 tile, 2-stage ring (32KB LDS -> 5 blocks/CU) ------
// R18 showed LDS 48KB caps occupancy at 3 blocks/CU (28%); with 2 stages the barrier
// vmcnt(0) waits the same 4 in-flight loads as the 3-stage vmcnt(4) (no younger loads
// exist), prefetch still lands during a full compute phase, and occupancy rises to 5.
__global__ __launch_bounds__(256) void gemm128(const f16* __restrict__ A, int lda, int zA,
                                               const f16* __restrict__ Bt, int ldb, int zB,
                                               const float* __restrict__ bias,
                                               f16* __restrict__ C, int ldc, int zC,
                                               float* __restrict__ Sf,
                                               int M, int Np, int K, int hcS, int Sw, int act) {
    __shared__ f16 smem[16384];   // 32 KB = 2 stages x (A 4096 + B 4096 f16)
    const int rm = blockIdx.x * 128;
    if (rm >= M) return;
    A  += (size_t)blockIdx.z * zA;
    Bt += (size_t)blockIdx.z * zB;
    C  += (size_t)blockIdx.z * zC;
    const int tid  = threadIdx.x;
    const int lane = tid & 63;
    const int wave = tid >> 6;
    const int l16  = lane & 15;
    const int quad = lane >> 4;
    const int cn   = blockIdx.y * 128;
    const int wrow = (wave >> 1) * 64;
    const int wcol = (wave & 1) * 64;

    const int rS  = tid >> 2;
    const int kc  = ((tid & 3) ^ ((tid >> 3) & 3)) << 3;
    int rowA0 = rm + rS;       if (rowA0 >= M) rowA0 = M - 1;
    int rowA1 = rm + rS + 64;  if (rowA1 >= M) rowA1 = M - 1;
    const f16* gA0 = A + (size_t)rowA0 * lda + kc;
    const f16* gA1 = A + (size_t)rowA1 * lda + kc;
    const f16* gB0 = Bt + (size_t)(cn + rS) * ldb + kc;
    const f16* gB1 = Bt + (size_t)(cn + rS + 64) * ldb + kc;

    const int swf = (l16 >> 1) & 3;
    const int rdAoff = (wrow + l16) * 32 + ((quad ^ swf) << 3);
    const int rdBoff = 4096 + (wcol + l16) * 32 + ((quad ^ swf) << 3);

    f32x4 acc[4][4] = {};

    auto stage_load = [&](int slot) {
        f16* base = smem + slot * 8192;
        async16(base + tid * 8, gA0);
        async16(base + tid * 8 + 2048, gA1);
        async16(base + 4096 + tid * 8, gB0);
        async16(base + 4096 + tid * 8 + 2048, gB1);
        gA0 += 32; gA1 += 32; gB0 += 32; gB1 += 32;
    };

    const int NI = K >> 5;
    stage_load(0);

    int slot = 0;
    for (int i = 0; i < NI; ++i) {
        asm volatile("s_waitcnt vmcnt(0)" ::: "memory");  // stage i's 4 loads (only ones in flight)
        asm volatile("s_barrier" ::: "memory");           // also: all waves done reading other buf
        if (i + 1 < NI) stage_load(slot ^ 1);             // lands during this compute phase
        const f16* sb = smem + slot * 8192;
        f16x8 av[4], bv[4];
#pragma unroll
        for (int ii = 0; ii < 4; ++ii) av[ii] = *(const f16x8*)(sb + rdAoff + ii * 512);
#pragma unroll
        for (int j = 0; j < 4; ++j) bv[j] = *(const f16x8*)(sb + rdBoff + j * 512);
#pragma unroll
        for (int ii = 0; ii < 4; ++ii)
#pragma unroll
            for (int j = 0; j < 4; ++j)
                acc[ii][j] = __builtin_amdgcn_mfma_f32_16x16x32_f16(bv[j], av[ii], acc[ii][j], 0, 0, 0);
        slot ^= 1;
    }
    __syncthreads();

    f16* sC = smem;    // 64 x 136 f16 = 17 KB (unions the 32 KB staging)
    for (int round = 0; round < 2; ++round) {
        if ((wave >> 1) == round) {
#pragma unroll
            for (int j = 0; j < 4; ++j) {
                const int cb = wcol + j * 16 + quad * 4;
                const float4 bb = *(const float4*)(bias + cn + cb);
#pragma unroll
                for (int i = 0; i < 4; ++i) {
                    const int r = i * 16 + l16;
                    float v0 = acc[i][j][0] + bb.x;
                    float v1 = acc[i][j][1] + bb.y;
                    float v2 = acc[i][j][2] + bb.z;
                    float v3 = acc[i][j][3] + bb.w;
                    if (act) {
                        v0 = v0 > 0.0f ? v0 : (__expf(v0) - 1.0f);
                        v1 = v1 > 0.0f ? v1 : (__expf(v1) - 1.0f);
                        v2 = v2 > 0.0f ? v2 : (__expf(v2) - 1.0f);
                        v3 = v3 > 0.0f ? v3 : (__expf(v3) - 1.0f);
                    }
                    f16x4 o;
                    o[0] = (f16)v0; o[1] = (f16)v1; o[2] = (f16)v2; o[3] = (f16)v3;
                    *(f16x4*)(sC + r * 136 + cb) = o;
                    if (Sf) {
                        const int sc = cn + cb - hcS;
                        if (sc >= 0 && sc < Sw) {
                            const int grow = rm + round * 64 + r;
                            if (grow < M) {
                                float4 sv = { v0, v1, v2, v3 };
                                *(float4*)(Sf + (size_t)grow * Sw + sc) = sv;
                            }
                        }
                    }
                }
            }
        }
        __syncthreads();
#pragma unroll
        for (int it = 0; it < 4; ++it) {
            const int r = it * 16 + (tid >> 4);
            const int ch = tid & 15;
            const int grow = rm + round * 64 + r;
            if (grow < M) {
                f16x8 v = *(const f16x8*)(sC + r * 136 + ch * 8);
                *(f16x8*)(C + (size_t)grow * ldc + cn + ch * 8) = v;
            }
        }
        __syncthreads();
    }
}

// ---------------- layer-1: alpha (Y-trick) + softmax + Z aggregation, fused ----------
__global__ __launch_bounds__(256) void alpha_zagg(const f16* __restrict__ Y, const f16* __restrict__ X,
                                                  const int* __restrict__ offs,
                                                  const int* __restrict__ srcCSR,
                                                  f16* __restrict__ Z,
                                                  int strideY, float scale) {
    const int fin = 128;
    const int n = blockIdx.x;
    const int e0 = offs[n];
    int d = offs[n + 1] - e0;
    if (d > 256) d = 256;

    __shared__ __align__(16) f16 sy[1024];
    __shared__ float sew[256 * NH];
    __shared__ float sv[256 * NH];
    __shared__ int sed[256];
    __shared__ float su[NH];
    __shared__ __align__(16) f16 sx[32 * 128];
    const int tid = threadIdx.x;

    const f16* Yn = Y + (size_t)n * strideY;
    for (int c = tid; c < fin; c += 256) ((f16x8*)sy)[c] = ((const f16x8*)Yn)[c];
    if (tid < NH) su[tid] = (float)Yn[8 * fin + tid];
    for (int e = tid; e < d; e += 256) {
        int s = srcCSR[e0 + e];
        sed[e] = s;
        f16x8 vv = *(const f16x8*)(Y + (size_t)s * strideY + 8 * fin + 8);
#pragma unroll
        for (int t = 0; t < 8; ++t) sv[e * NH + t] = (float)vv[t];
    }
    __syncthreads();

    {
        const int wv = tid >> 6, lane = tid & 63;
        for (int e = wv; e < d; e += 4) {
            const f16x8* kg = (const f16x8*)(X + (size_t)sed[e] * fin);
#pragma unroll
            for (int p = 0; p < 2; ++p) {
                const int ci = p * 64 + lane;
                const int head = ci >> 4;
                const int kcn = ci & 15;
                f16x8 yv = ((const f16x8*)sy)[ci];
                f16x8 xv = kg[kcn];
                float acc = 0.0f;
#pragma unroll
                for (int t = 0; t < 8; ++t) acc += (float)yv[t] * (float)xv[t];
#pragma unroll
                for (int o = 8; o > 0; o >>= 1) acc += __shfl_down(acc, o, 16);
                if ((lane & 15) == 0)
                    sew[e * NH + head] = (acc + su[head] + sv[e * NH + head]) * scale;
            }
        }
    }
    __syncthreads();

    if (tid < NH) {
        const int h = tid;
        float m = -3.0e38f;
        for (int e = 0; e < d; ++e) m = fmaxf(m, sew[e * NH + h]);
        float den = 0.0f;
        for (int e = 0; e < d; ++e) {
            float ex = __expf(sew[e * NH + h] - m);
            sew[e * NH + h] = ex;
            den += ex;
        }
        float inv = 1.0f / (fmaxf(den, 1e-16f) * (float)NH);
        for (int e = 0; e < d; ++e) sew[e * NH + h] *= inv;
    }
    __syncthreads();

    const int h = tid >> 5;
    const int f0 = (tid * 4) & 127;
    float a0 = 0.0f, a1 = 0.0f, a2 = 0.0f, a3 = 0.0f;
    for (int ch = 0; ch < d; ch += 32) {
        const int cnt = min(32, d - ch);
        for (int idx = tid; idx < cnt * 16; idx += 256) {
            int row = idx >> 4, c8 = idx & 15;
            *(f16x8*)(sx + row * 128 + c8 * 8) = *(const f16x8*)(X + (size_t)sed[ch + row] * 128 + c8 * 8);
        }
        __syncthreads();
        for (int e = 0; e < cnt; ++e) {
            float w = sew[(ch + e) * NH + h];
            f16x4 xv = *(const f16x4*)(sx + e * 128 + f0);
            a0 += w * (float)xv[0];
            a1 += w * (float)xv[1];
            a2 += w * (float)xv[2];
            a3 += w * (float)xv[3];
        }
        __syncthreads();
    }
    f16* Zr = Z + (size_t)n * 1184;
    f16x4 o; o[0] = (f16)a0; o[1] = (f16)a1; o[2] = (f16)a2; o[3] = (f16)a3;
    *(f16x4*)(Zr + tid * 4) = o;
    if (tid < 16) *(f16x8*)(Zr + 1024 + tid * 8) = *(const f16x8*)(X + (size_t)n * 128 + tid * 8);
    if (tid >= 32 && tid < 40) {
        int hh = tid - 32;
        float s = 0.0f;
        for (int e = 0; e < d; ++e) s += sew[e * NH + hh];
        Zr[1152 + hh] = (f16)s;
    }
    if (tid >= 64 && tid < 88) Zr[1160 + (tid - 64)] = (f16)0.0f;
}

// ---------------- layers 2,3: logits + softmax + V aggregation + skip + ELU, fused ----
__global__ __launch_bounds__(256) void edge_node(const f16* __restrict__ QKVS,
                                                 const float* __restrict__ Sf,
                                                 const int* __restrict__ offs,
                                                 const int* __restrict__ srcCSR,
                                                 float* __restrict__ hout, f16* __restrict__ houth,
                                                 int Np, int C, int hc, float scale, int writeHout) {
    const int n = blockIdx.x;
    const int e0 = offs[n];
    int d = offs[n + 1] - e0;
    if (d > 256) d = 256;

    __shared__ __align__(16) f16 sq[4096];
    __shared__ float sew[256 * NH];
    __shared__ int sed[256];
    __shared__ float sred[512];
    const int tid = threadIdx.x;

    const f16x8* qg = (const f16x8*)(QKVS + (size_t)n * Np);
    const int qchunks = hc >> 3;
    for (int c = tid; c < qchunks; c += 256) ((f16x8*)sq)[c] = qg[c];
    for (int e = tid; e < d; e += 256) sed[e] = srcCSR[e0 + e];
    __syncthreads();

    {
        const int wv = tid >> 6, lane = tid & 63;
        const int cph = C >> 3;
        const int passes = (hc >> 9) ? (hc >> 9) : 1;
        for (int e = wv; e < d; e += 4) {
            const f16x8* kg = (const f16x8*)(QKVS + (size_t)sed[e] * Np + hc);
            for (int p = 0; p < passes; ++p) {
                const int ci = p * 64 + lane;
                f16x8 qv = ((const f16x8*)sq)[ci];
                f16x8 kv = kg[ci];
                float acc = 0.0f;
#pragma unroll
                for (int t = 0; t < 8; ++t) acc += (float)qv[t] * (float)kv[t];
                for (int o = cph >> 1; o > 0; o >>= 1) acc += __shfl_down(acc, o, cph);
                if ((lane & (cph - 1)) == 0) {
                    const int head = ci / cph;
                    sew[e * NH + head] = acc * scale;
                }
            }
        }
    }
    __syncthreads();

    if (tid < NH) {
        const int h = tid;
        float m = -3.0e38f;
        for (int e = 0; e < d; ++e) m = fmaxf(m, sew[e * NH + h]);
        float den = 0.0f;
        for (int e = 0; e < d; ++e) {
            float ex = __expf(sew[e * NH + h] - m);
            sew[e * NH + h] = ex;
            den += ex;
        }
        float inv = 1.0f / (fmaxf(den, 1e-16f) * (float)NH);
        for (int e = 0; e < d; ++e) sew[e * NH + h] *= inv;
    }
    __syncthreads();

    const int half = C >> 1;
    const int cp = tid & (half - 1);
    const int grp = tid / half;
    const int ngr = 256 / half;
    float a0 = 0.0f, a1 = 0.0f;
    for (int e = grp; e < d; e += ngr) {
        const unsigned int* vp = (const unsigned int*)(QKVS + (size_t)sed[e] * Np + 2 * hc);
#pragma unroll
        for (int h = 0; h < NH; ++h) {
            float w = sew[e * NH + h];
            f16x2 vv = __builtin_bit_cast(f16x2, vp[((h * C) >> 1) + cp]);
            a0 += w * (float)vv.x;
            a1 += w * (float)vv.y;
        }
    }
    if (ngr > 1) {
        sred[tid] = a0;
        sred[256 + tid] = a1;
        __syncthreads();
        if (grp == 0) {
            for (int g = 1; g < ngr; ++g) {
                a0 += sred[g * half + cp];
                a1 += sred[256 + g * half + cp];
            }
        }
    }
    if (grp == 0) {
        const int c = cp * 2;
        const float* Sp = Sf + (size_t)n * C;
        float o0 = a0 + Sp[c];
        float o1 = a1 + Sp[c + 1];
        o0 = o0 > 0.0f ? o0 : (__expf(o0) - 1.0f);
        o1 = o1 > 0.0f ? o1 : (__expf(o1) - 1.0f);
        if (writeHout) {
            hout[(size_t)n * C + c] = o0;
            hout[(size_t)n * C + c + 1] = o1;
        }
        houth[(size_t)n * C + c] = (f16)o0;
        houth[(size_t)n * C + c + 1] = (f16)o1;
    }
}

// ---------------- fused pooling + final FC ----------------
__global__ __launch_bounds__(256) void pool_graph(const float* __restrict__ h,
                                                  const float* __restrict__ gw, const float* __restrict__ gb,
                                                  const float* __restrict__ fcw, const float* __restrict__ fcb,
                                                  const int* __restrict__ goffs,
                                                  float* __restrict__ gbuf, float* __restrict__ out) {
    const int g = blockIdx.x;
    const int s = goffs[g], e = goffs[g + 1];
    const int tid = threadIdx.x;
    const int wv = tid >> 6, lane = tid & 63;

    __shared__ float red[256];
    __shared__ float pl[64];
    __shared__ float sden;

    if (e == s) {
        if (tid < 10) out[g * 10 + tid] = fcb[tid];
        return;
    }

    const float gwl = gw[lane];
    for (int n = s + wv; n < e; n += 4) {
        float acc = h[(size_t)n * 64 + lane] * gwl;
#pragma unroll
        for (int o = 32; o > 0; o >>= 1) acc += __shfl_down(acc, o, 64);
        if (lane == 0) gbuf[n] = acc + gb[0];
    }
    __syncthreads();

    float m = -3.0e38f;
    for (int n = s + tid; n < e; n += 256) m = fmaxf(m, gbuf[n]);
    red[tid] = m;
    __syncthreads();
    for (int o = 128; o > 0; o >>= 1) {
        if (tid < o) red[tid] = fmaxf(red[tid], red[tid + o]);
        __syncthreads();
    }
    m = red[0];
    __syncthreads();

    float sum = 0.0f;
    for (int n = s + tid; n < e; n += 256) {
        float ex = __expf(gbuf[n] - m);
        gbuf[n] = ex;
        sum += ex;
    }
    red[tid] = sum;
    __syncthreads();
    for (int o = 128; o > 0; o >>= 1) {
        if (tid < o) red[tid] += red[tid + o];
        __syncthreads();
    }
    if (tid == 0) sden = 1.0f / fmaxf(red[0], 1e-16f);
    __syncthreads();

    float acc = 0.0f;
    for (int n = s + wv; n < e; n += 4) acc += gbuf[n] * h[(size_t)n * 64 + lane];
    red[tid] = acc;
    __syncthreads();
    if (wv == 0) pl[lane] = (red[lane] + red[64 + lane] + red[128 + lane] + red[192 + lane]) * sden;
    __syncthreads();

    if (tid < 10) {
        float o = fcb[tid];
#pragma unroll
        for (int c = 0; c < 64; ++c) o += pl[c] * fcw[c * 10 + tid];
        out[g * 10 + tid] = o;
    }
}

// ---------------- host ----------------
extern "C" void kernel_launch(void* const* d_in, const int* in_sizes, int n_in,
                              void* d_out, int out_size, void* d_ws, size_t ws_size,
                              hipStream_t stream) {
    const float* x   = (const float*)d_in[0];
    const int* ei    = (const int*)d_in[1];
    const int* src   = ei;
    const int* dst   = ei + NE;
    const int* batch = (const int*)d_in[2];

    struct LayerW { int fin, C, hc; const float *qw,*qb,*kw,*kb,*vw,*vb,*sw,*sb; };
    LayerW LW[3];
    const int fins[3] = {128, 512, 256};
    const int Cs[3]   = {512, 256, 64};
    for (int l = 0; l < 3; ++l) {
        int b = 3 + 8 * l;
        LW[l].fin = fins[l]; LW[l].C = Cs[l]; LW[l].hc = Cs[l] * NH;
        LW[l].qw = (const float*)d_in[b + 0]; LW[l].qb = (const float*)d_in[b + 1];
        LW[l].kw = (const float*)d_in[b + 2]; LW[l].kb = (const float*)d_in[b + 3];
        LW[l].vw = (const float*)d_in[b + 4]; LW[l].vb = (const float*)d_in[b + 5];
        LW[l].sw = (const float*)d_in[b + 6]; LW[l].sb = (const float*)d_in[b + 7];
    }
    const float* gate_w = (const float*)d_in[27];
    const float* gate_b = (const float*)d_in[28];
    const float* fc_w   = (const float*)d_in[29];
    const float* fc_b   = (const float*)d_in[30];

    size_t off = 0;
    char* ws = (char*)d_ws;
    auto alloc = [&](size_t bytes) -> void* {
        void* p = ws + off;
        off = (off + bytes + 255) & ~(size_t)255;
        return p;
    };
    f16* BtL2   = (f16*)alloc((size_t)6400 * 512 * sizeof(f16));
    f16* BtL3   = (f16*)alloc((size_t)1664 * 256 * sizeof(f16));
    f16* BtZ    = (f16*)alloc((size_t)512 * 1184 * sizeof(f16));
    float* biasL2 = (float*)alloc(6400 * sizeof(float));
    float* biasL3 = (float*)alloc(1664 * sizeof(float));
    float* biasZ  = (float*)alloc(512 * sizeof(float));
    f16* QKbuf  = (f16*)alloc((size_t)NN * 6400 * sizeof(f16));
    f16* Zbuf   = (f16*)alloc((size_t)NN * 1184 * sizeof(f16));
    float* Sf   = (float*)alloc((size_t)NN * 256 * sizeof(float));
    f16* xh     = (f16*)alloc((size_t)NN * 128 * sizeof(f16));
    f16* houth  = (f16*)alloc((size_t)NN * 512 * sizeof(f16));
    float* hf   = (float*)alloc((size_t)NN * 64 * sizeof(float));
    f16* qw16   = (f16*)alloc((size_t)128 * 4096 * sizeof(f16));
    f16* kw16   = (f16*)alloc((size_t)128 * 4096 * sizeof(f16));
    f16* BtY    = (f16*)alloc((size_t)1152 * 128 * sizeof(f16));
    float* zbias = (float*)alloc(512 * sizeof(float));
    float* biasY = (float*)alloc(1152 * sizeof(float));
    int* deg    = (int*)alloc(NN * sizeof(int));
    int* offs   = (int*)alloc((NN + 1) * sizeof(int));
    int* cursor = (int*)alloc(NN * sizeof(int));
    int* srcCSR = (int*)alloc(NE * sizeof(int));
    int* goffs  = (int*)alloc((NG + 1) * sizeof(int));
    float* gbuf = (float*)alloc(NN * sizeof(float));
    if (off > ws_size) return;

    megaprep<<<MB_TOTAL, 256, 0, stream>>>(
        x, xh, LW[0].qw, qw16, LW[0].kw, kw16,
        LW[0].qb, LW[0].kb, LW[0].vw, LW[0].sw, LW[0].vb, LW[0].sb,
        LW[1].qw, LW[1].qb, LW[1].kw, LW[1].kb, LW[1].vw, LW[1].vb, LW[1].sw, LW[1].sb,
        LW[2].qw, LW[2].qb, LW[2].kw, LW[2].kb, LW[2].vw, LW[2].vb, LW[2].sw, LW[2].sb,
        BtL2, biasL2, BtL3, biasL3, BtZ, biasZ, BtY, biasY, zbias, deg);

    hist_kernel<<<(NE + 255) / 256, 256, 0, stream>>>(dst, deg, NE);
    scan_goffs<<<2, 1024, 0, stream>>>(deg, offs, cursor, batch, goffs);
    scatter_kernel<<<(NE + 255) / 256, 256, 0, stream>>>(src, dst, cursor, srcCSR, NE);
    sort_csr<<<(NN + 255) / 256, 256, 0, stream>>>(offs, srcCSR);

    const int grid_m = 80;   // mult of 8: XCD-stable across y-passes

    // ---- layer 1: Y-trick alpha + fused softmax + Z aggregation + Z-GEMM ----
    {
        const int fin = 128, hc = 4096, NtotY = 1152;
        const float scale = 1.0f / sqrtf(512.0f);
        dim3 gm(1, 1, 8);
        gemm128<<<gm, 256, 0, stream>>>(kw16, hc, 512, qw16, hc, 512, zbias,
                                        BtY, fin, fin * fin, nullptr, fin, fin, 512, 0, 0, 0);
        dim3 gy(grid_m, NtotY / 128);
        gemm128<<<gy, 256, 0, stream>>>(xh, fin, 0, BtY, fin, 0, biasY,
                                        QKbuf, NtotY, 0, nullptr, NN, NtotY, fin, 0, 0, 0);
        alpha_zagg<<<NN, 256, 0, stream>>>(QKbuf, xh, offs, srcCSR, Zbuf, NtotY, scale);
        dim3 gz(grid_m, 4);
        gemm128<<<gz, 256, 0, stream>>>(Zbuf, 1184, 0, BtZ, 1184, 0, biasZ,
                                        houth, 512, 0, nullptr, NN, 512, 1184, 0, 0, 1);
    }
    // ---- layers 2,3: fused Q|K|V|S GEMM + fused edge/node kernel ----
    const f16* Acur = houth;
    for (int l = 1; l < 3; ++l) {
        const int K = LW[l].fin, C = LW[l].C, hc = LW[l].hc;
        const float scale = 1.0f / sqrtf((float)C);
        const int Np = (3 * hc + C + 127) & ~127;   // L2: 6400, L3: 1664
        f16* Bt = (l == 1) ? BtL2 : BtL3;
        float* bias = (l == 1) ? biasL2 : biasL3;
        dim3 gq(grid_m, Np / 128);
        gemm128<<<gq, 256, 0, stream>>>(Acur, K, 0, Bt, K, 0, bias,
                                        QKbuf, Np, 0, Sf, NN, Np, K, 3 * hc, C, 0);
        edge_node<<<NN, 256, 0, stream>>>(QKbuf, Sf, offs, srcCSR, hf, houth,
                                          Np, C, hc, scale, l == 2 ? 1 : 0);
        Acur = houth;
    }

    pool_graph<<<NG, 256, 0, stream>>>(hf, gate_w, gate_b, fc_w, fc_b, goffs, gbuf, (float*)d_out);
}

// Round 20
// 460.662 us; speedup vs baseline: 1.0294x; 1.0294x over previous
//
#include <hip/hip_runtime.h>
#include <stdint.h>
#include <math.h>

#define NN 10000
#define NE 30000
#define NG 50
#define NH 8

typedef _Float16 f16;
typedef _Float16 f16x2 __attribute__((ext_vector_type(2)));
typedef _Float16 f16x4 __attribute__((ext_vector_type(4)));
typedef _Float16 f16x8 __attribute__((ext_vector_type(8)));
typedef float f32x4 __attribute__((ext_vector_type(4)));

// ---------------- helpers ----------------
__device__ inline void async16(f16* l, const f16* g) {
    __builtin_amdgcn_global_load_lds((const __attribute__((address_space(1))) void*)g,
                                     (__attribute__((address_space(3))) void*)l, 16, 0, 0);
}

// ---------------- CSR build (parallel multi-kernel; R15-proven) ----------------
__global__ void hist_kernel(const int* __restrict__ dst, int* __restrict__ deg, int E) {
    int e = blockIdx.x * blockDim.x + threadIdx.x;
    if (e < E) atomicAdd(&deg[dst[e]], 1);
}

__global__ __launch_bounds__(1024) void scan_goffs(const int* __restrict__ deg, int* __restrict__ offs,
                                                   int* __restrict__ cursor,
                                                   const int* __restrict__ batch, int* __restrict__ goffs) {
    if (blockIdx.x == 1) {
        int g = threadIdx.x;
        if (g > NG) return;
        int lo = 0, hi = NN;
        while (lo < hi) {
            int mid = (lo + hi) >> 1;
            if (batch[mid] < g) lo = mid + 1; else hi = mid;
        }
        goffs[g] = lo;
        return;
    }
    __shared__ int tot[1024];
    const int t = threadIdx.x;
    const int base = t * 10;
    int v[10];
    int s = 0;
#pragma unroll
    for (int i = 0; i < 10; ++i) {
        int idx = base + i;
        v[i] = (idx < NN) ? deg[idx] : 0;
        s += v[i];
    }
    tot[t] = s;
    __syncthreads();
    for (int d2 = 1; d2 < 1024; d2 <<= 1) {
        int add = (t >= d2) ? tot[t - d2] : 0;
        __syncthreads();
        tot[t] += add;
        __syncthreads();
    }
    int run = tot[t] - s;
    if (t == 0) offs[0] = 0;
#pragma unroll
    for (int i = 0; i < 10; ++i) {
        int idx = base + i;
        if (idx < NN) cursor[idx] = run;
        run += v[i];
        if (idx < NN) offs[idx + 1] = run;
    }
}

__global__ void scatter_kernel(const int* __restrict__ src, const int* __restrict__ dst,
                               int* __restrict__ cursor, int* __restrict__ srcCSR, int E) {
    int e = blockIdx.x * blockDim.x + threadIdx.x;
    if (e < E) {
        int p = atomicAdd(&cursor[dst[e]], 1);
        srcCSR[p] = src[e];
    }
}

// per-segment insertion sort -> deterministic CSR (fixed fp32 summation orders)
__global__ void sort_csr(const int* __restrict__ offs, int* __restrict__ srcCSR) {
    int n = blockIdx.x * blockDim.x + threadIdx.x;
    if (n >= NN) return;
    int s = offs[n], e = offs[n + 1];
    for (int i = s + 1; i < e; ++i) {
        int v = srcCSR[i];
        int j = i - 1;
        while (j >= s && srcCSR[j] > v) { srcCSR[j + 1] = srcCSR[j]; --j; }
        srcCSR[j + 1] = v;
    }
}

// ---------------- megaprep: all conversions + weight preps + zero-init, ONE dispatch --
#define MB_CVTX   0
#define MB_CVTQ   5000
#define MB_CVTK   7048
#define MB_P4L2   9096
#define MB_P4L3   9896
#define MB_PZB    10000
#define MB_PU     10296
#define MB_ZERO   10808
#define MB_TOTAL  10854

__device__ void prep4_tile(const float* __restrict__ W0, int n0, const float* __restrict__ W1, int n1,
                           const float* __restrict__ W2, int n2, const float* __restrict__ W3, int n3,
                           const float* __restrict__ b0, const float* __restrict__ b1,
                           const float* __restrict__ b2, const float* __restrict__ b3,
                           f16* __restrict__ Bt, float* __restrict__ bias, int K, int bx, int by) {
    __shared__ float tile[64][65];
    const int k0 = bx * 64;
    const int nb = by * 64;
    const int tid = threadIdx.x;
    const int tn = tid & 63;
    const int t4 = tid >> 6;
#pragma unroll
    for (int i = 0; i < 16; ++i) {
        int kl = t4 + i * 4;
        int k = k0 + kl;
        int n = nb + tn;
        float w = 0.0f;
        int m = n;
        if (m < n0) w = W0[(size_t)k * n0 + m];
        else { m -= n0;
            if (m < n1) w = W1[(size_t)k * n1 + m];
            else { m -= n1;
                if (m < n2) w = W2[(size_t)k * n2 + m];
                else { m -= n2; if (m < n3) w = W3[(size_t)k * n3 + m]; }
            }
        }
        tile[kl][tn] = w;
    }
    if (bx == 0 && t4 == 0) {
        int n = nb + tn;
        float bv = 0.0f;
        int m = n;
        if (m < n0) bv = b0[m];
        else { m -= n0;
            if (m < n1) bv = b1[m];
            else { m -= n1;
                if (m < n2) bv = b2[m];
                else { m -= n2; if (m < n3) bv = b3[m]; }
            }
        }
        bias[n] = bv;
    }
    __syncthreads();
#pragma unroll
    for (int i = 0; i < 16; ++i) {
        int nl = t4 + i * 4;
        Bt[(size_t)(nb + nl) * K + k0 + tn] = (f16)tile[tn][nl];
    }
}

__global__ __launch_bounds__(256) void megaprep(
        const float* __restrict__ x, f16* __restrict__ xh,
        const float* __restrict__ qw1, f16* __restrict__ qw16,
        const float* __restrict__ kw1, f16* __restrict__ kw16,
        const float* __restrict__ qb1, const float* __restrict__ kb1,
        const float* __restrict__ vw1, const float* __restrict__ sw1,
        const float* __restrict__ vb1, const float* __restrict__ sb1,
        const float* __restrict__ qw2, const float* __restrict__ qb2,
        const float* __restrict__ kw2, const float* __restrict__ kb2,
        const float* __restrict__ vw2, const float* __restrict__ vb2,
        const float* __restrict__ sw2, const float* __restrict__ sb2,
        const float* __restrict__ qw3, const float* __restrict__ qb3,
        const float* __restrict__ kw3, const float* __restrict__ kb3,
        const float* __restrict__ vw3, const float* __restrict__ vb3,
        const float* __restrict__ sw3, const float* __restrict__ sb3,
        f16* __restrict__ BtL2, float* __restrict__ biasL2,
        f16* __restrict__ BtL3, float* __restrict__ biasL3,
        f16* __restrict__ BtZ, float* __restrict__ biasZ,
        f16* __restrict__ BtY, float* __restrict__ biasY,
        float* __restrict__ zbias, int* __restrict__ deg) {
    const int b = blockIdx.x;
    const int tid = threadIdx.x;

    if (b < MB_CVTQ) {
        int i = b * 256 + tid;
        if (i < NN * 128) xh[i] = (f16)x[i];
    } else if (b < MB_CVTK) {
        int i = (b - MB_CVTQ) * 256 + tid;
        qw16[i] = (f16)qw1[i];
    } else if (b < MB_P4L2) {
        int i = (b - MB_CVTK) * 256 + tid;
        kw16[i] = (f16)kw1[i];
    } else if (b < MB_P4L3) {
        int r = b - MB_P4L2;
        prep4_tile(qw2, 2048, kw2, 2048, vw2, 2048, sw2, 256,
                   qb2, kb2, vb2, sb2, BtL2, biasL2, 512, r & 7, r >> 3);
    } else if (b < MB_PZB) {
        int r = b - MB_P4L3;
        prep4_tile(qw3, 512, kw3, 512, vw3, 512, sw3, 64,
                   qb3, kb3, vb3, sb3, BtL3, biasL3, 256, r & 3, r >> 2);
    } else if (b < MB_PU) {
        int r = b - MB_PZB;
        int bx = r % 37, by = r / 37;
        __shared__ f16 ztile[32][65];
        const int k0 = bx * 32, c0 = by * 64;
#pragma unroll
        for (int i = 0; i < 8; ++i) {
            int idx = tid + i * 256;
            int kl = idx >> 6, cl = idx & 63;
            int k = k0 + kl, c = c0 + cl;
            float v = 0.0f;
            if (k < 1024)      v = vw1[(size_t)(k & 127) * 4096 + (k >> 7) * 512 + c];
            else if (k < 1152) v = sw1[(size_t)(k - 1024) * 512 + c];
            else if (k < 1160) v = vb1[(k - 1152) * 512 + c];
            ztile[kl][cl] = (f16)v;
        }
        if (bx == 0 && tid < 64) biasZ[c0 + tid] = sb1[c0 + tid];
        __syncthreads();
        const int cl = tid >> 2, kl = (tid & 3) * 8;
        f16x8 v;
#pragma unroll
        for (int t2 = 0; t2 < 8; ++t2) v[t2] = ztile[kl + t2][cl];
        *(f16x8*)(BtZ + (size_t)(c0 + cl) * 1184 + k0 + kl) = v;
    } else if (b < MB_ZERO) {
        const int fin = 128, hc = 4096, C = 512;
        const int wid = (b - MB_PU) * 4 + (tid >> 6);
        const int lane = tid & 63;
        if (wid >= fin * 16) return;
        const int k = wid >> 4;
        const int idx = wid & 15;
        const int h = idx & 7, isV = idx >> 3;
        const float* W = isV ? kw1 : qw1;
        const float* bvec = isV ? qb1 : kb1;
        float s = 0.0f;
        for (int c = lane; c < C; c += 64) s += W[(size_t)k * hc + h * C + c] * bvec[h * C + c];
#pragma unroll
        for (int o = 32; o > 0; o >>= 1) s += __shfl_down(s, o, 64);
        if (lane == 0) BtY[(size_t)(8 * fin + isV * 8 + h) * fin + k] = (f16)s;
        if (wid < 8) {
            float cc = 0.0f;
            for (int c = lane; c < C; c += 64) cc += qb1[wid * C + c] * kb1[wid * C + c];
#pragma unroll
            for (int o = 32; o > 0; o >>= 1) cc += __shfl_down(cc, o, 64);
            if (lane == 0) biasY[8 * fin + wid] = cc;
        }
    } else {
        int idx = (b - MB_ZERO) * 256 + tid;
        if (idx < 512) zbias[idx] = 0.0f;
        else if (idx < 1536) biasY[idx - 512] = 0.0f;
        else if (idx < 1656) biasY[1032 + idx - 1536] = 0.0f;
        else if (idx < 1656 + NN) deg[idx - 1656] = 0;
    }
}

// ---------------- gemm128: 128x128 tile, 3-stage ring, vmcnt(4) (R18-proven optimum) --
// Neighbors measured worse: 2-stage/32KB = 112us (prefetch distance 1 < load latency),
// 128x256 tile = 100-112us (VGPR/occupancy), so 3-stage distance-2 is the local optimum.
__global__ __launch_bounds__(256) void gemm128(const f16* __restrict__ A, int lda, int zA,
                                               const f16* __restrict__ Bt, int ldb, int zB,
                                               const float* __restrict__ bias,
                                               f16* __restrict__ C, int ldc, int zC,
                                               float* __restrict__ Sf,
                                               int M, int Np, int K, int hcS, int Sw, int act) {
    __shared__ f16 smem[24576];   // 48 KB = 3 stages x (A 4096 + B 4096 f16)
    const int rm = blockIdx.x * 128;
    if (rm >= M) return;
    A  += (size_t)blockIdx.z * zA;
    Bt += (size_t)blockIdx.z * zB;
    C  += (size_t)blockIdx.z * zC;
    const int tid  = threadIdx.x;
    const int lane = tid & 63;
    const int wave = tid >> 6;
    const int l16  = lane & 15;
    const int quad = lane >> 4;
    const int cn   = blockIdx.y * 128;
    const int wrow = (wave >> 1) * 64;
    const int wcol = (wave & 1) * 64;

    const int rS  = tid >> 2;
    const int kc  = ((tid & 3) ^ ((tid >> 3) & 3)) << 3;
    int rowA0 = rm + rS;       if (rowA0 >= M) rowA0 = M - 1;
    int rowA1 = rm + rS + 64;  if (rowA1 >= M) rowA1 = M - 1;
    const f16* gA0 = A + (size_t)rowA0 * lda + kc;
    const f16* gA1 = A + (size_t)rowA1 * lda + kc;
    const f16* gB0 = Bt + (size_t)(cn + rS) * ldb + kc;
    const f16* gB1 = Bt + (size_t)(cn + rS + 64) * ldb + kc;

    const int swf = (l16 >> 1) & 3;
    const int rdAoff = (wrow + l16) * 32 + ((quad ^ swf) << 3);
    const int rdBoff = 4096 + (wcol + l16) * 32 + ((quad ^ swf) << 3);

    f32x4 acc[4][4] = {};

    auto stage_load = [&](int slot) {
        f16* base = smem + slot * 8192;
        async16(base + tid * 8, gA0);
        async16(base + tid * 8 + 2048, gA1);
        async16(base + 4096 + tid * 8, gB0);
        async16(base + 4096 + tid * 8 + 2048, gB1);
        gA0 += 32; gA1 += 32; gB0 += 32; gB1 += 32;
    };

    const int NI = K >> 5;
    stage_load(0);
    stage_load(1);

    int slot = 0;
    for (int i = 0; i < NI; ++i) {
        if (i + 1 < NI) asm volatile("s_waitcnt vmcnt(4)" ::: "memory");
        else            asm volatile("s_waitcnt vmcnt(0)" ::: "memory");
        asm volatile("s_barrier" ::: "memory");
        if (i + 2 < NI) {
            int s2 = slot + 2; if (s2 >= 3) s2 -= 3;
            stage_load(s2);
        }
        const f16* sb = smem + slot * 8192;
        f16x8 av[4], bv[4];
#pragma unroll
        for (int ii = 0; ii < 4; ++ii) av[ii] = *(const f16x8*)(sb + rdAoff + ii * 512);
#pragma unroll
        for (int j = 0; j < 4; ++j) bv[j] = *(const f16x8*)(sb + rdBoff + j * 512);
#pragma unroll
        for (int ii = 0; ii < 4; ++ii)
#pragma unroll
            for (int j = 0; j < 4; ++j)
                acc[ii][j] = __builtin_amdgcn_mfma_f32_16x16x32_f16(bv[j], av[ii], acc[ii][j], 0, 0, 0);
        ++slot; if (slot == 3) slot = 0;
    }
    __syncthreads();

    f16* sC = smem;
    for (int round = 0; round < 2; ++round) {
        if ((wave >> 1) == round) {
#pragma unroll
            for (int j = 0; j < 4; ++j) {
                const int cb = wcol + j * 16 + quad * 4;
                const float4 bb = *(const float4*)(bias + cn + cb);
#pragma unroll
                for (int i = 0; i < 4; ++i) {
                    const int r = i * 16 + l16;
                    float v0 = acc[i][j][0] + bb.x;
                    float v1 = acc[i][j][1] + bb.y;
                    float v2 = acc[i][j][2] + bb.z;
                    float v3 = acc[i][j][3] + bb.w;
                    if (act) {
                        v0 = v0 > 0.0f ? v0 : (__expf(v0) - 1.0f);
                        v1 = v1 > 0.0f ? v1 : (__expf(v1) - 1.0f);
                        v2 = v2 > 0.0f ? v2 : (__expf(v2) - 1.0f);
                        v3 = v3 > 0.0f ? v3 : (__expf(v3) - 1.0f);
                    }
                    f16x4 o;
                    o[0] = (f16)v0; o[1] = (f16)v1; o[2] = (f16)v2; o[3] = (f16)v3;
                    *(f16x4*)(sC + r * 136 + cb) = o;
                    if (Sf) {
                        const int sc = cn + cb - hcS;
                        if (sc >= 0 && sc < Sw) {
                            const int grow = rm + round * 64 + r;
                            if (grow < M) {
                                float4 sv = { v0, v1, v2, v3 };
                                *(float4*)(Sf + (size_t)grow * Sw + sc) = sv;
                            }
                        }
                    }
                }
            }
        }
        __syncthreads();
#pragma unroll
        for (int it = 0; it < 4; ++it) {
            const int r = it * 16 + (tid >> 4);
            const int ch = tid & 15;
            const int grow = rm + round * 64 + r;
            if (grow < M) {
                f16x8 v = *(const f16x8*)(sC + r * 136 + ch * 8);
                *(f16x8*)(C + (size_t)grow * ldc + cn + ch * 8) = v;
            }
        }
        __syncthreads();
    }
}

// ---------------- layer-1: alpha (Y-trick) + softmax + Z aggregation, fused ----------
__global__ __launch_bounds__(256) void alpha_zagg(const f16* __restrict__ Y, const f16* __restrict__ X,
                                                  const int* __restrict__ offs,
                                                  const int* __restrict__ srcCSR,
                                                  f16* __restrict__ Z,
                                                  int strideY, float scale) {
    const int fin = 128;
    const int n = blockIdx.x;
    const int e0 = offs[n];
    int d = offs[n + 1] - e0;
    if (d > 256) d = 256;

    __shared__ __align__(16) f16 sy[1024];
    __shared__ float sew[256 * NH];
    __shared__ float sv[256 * NH];
    __shared__ int sed[256];
    __shared__ float su[NH];
    __shared__ __align__(16) f16 sx[32 * 128];
    const int tid = threadIdx.x;

    const f16* Yn = Y + (size_t)n * strideY;
    for (int c = tid; c < fin; c += 256) ((f16x8*)sy)[c] = ((const f16x8*)Yn)[c];
    if (tid < NH) su[tid] = (float)Yn[8 * fin + tid];
    for (int e = tid; e < d; e += 256) {
        int s = srcCSR[e0 + e];
        sed[e] = s;
        f16x8 vv = *(const f16x8*)(Y + (size_t)s * strideY + 8 * fin + 8);
#pragma unroll
        for (int t = 0; t < 8; ++t) sv[e * NH + t] = (float)vv[t];
    }
    __syncthreads();

    {
        const int wv = tid >> 6, lane = tid & 63;
        for (int e = wv; e < d; e += 4) {
            const f16x8* kg = (const f16x8*)(X + (size_t)sed[e] * fin);
#pragma unroll
            for (int p = 0; p < 2; ++p) {
                const int ci = p * 64 + lane;
                const int head = ci >> 4;
                const int kcn = ci & 15;
                f16x8 yv = ((const f16x8*)sy)[ci];
                f16x8 xv = kg[kcn];
                float acc = 0.0f;
#pragma unroll
                for (int t = 0; t < 8; ++t) acc += (float)yv[t] * (float)xv[t];
#pragma unroll
                for (int o = 8; o > 0; o >>= 1) acc += __shfl_down(acc, o, 16);
                if ((lane & 15) == 0)
                    sew[e * NH + head] = (acc + su[head] + sv[e * NH + head]) * scale;
            }
        }
    }
    __syncthreads();

    if (tid < NH) {
        const int h = tid;
        float m = -3.0e38f;
        for (int e = 0; e < d; ++e) m = fmaxf(m, sew[e * NH + h]);
        float den = 0.0f;
        for (int e = 0; e < d; ++e) {
            float ex = __expf(sew[e * NH + h] - m);
            sew[e * NH + h] = ex;
            den += ex;
        }
        float inv = 1.0f / (fmaxf(den, 1e-16f) * (float)NH);
        for (int e = 0; e < d; ++e) sew[e * NH + h] *= inv;
    }
    __syncthreads();

    const int h = tid >> 5;
    const int f0 = (tid * 4) & 127;
    float a0 = 0.0f, a1 = 0.0f, a2 = 0.0f, a3 = 0.0f;
    for (int ch = 0; ch < d; ch += 32) {
        const int cnt = min(32, d - ch);
        for (int idx = tid; idx < cnt * 16; idx += 256) {
            int row = idx >> 4, c8 = idx & 15;
            *(f16x8*)(sx + row * 128 + c8 * 8) = *(const f16x8*)(X + (size_t)sed[ch + row] * 128 + c8 * 8);
        }
        __syncthreads();
        for (int e = 0; e < cnt; ++e) {
            float w = sew[(ch + e) * NH + h];
            f16x4 xv = *(const f16x4*)(sx + e * 128 + f0);
            a0 += w * (float)xv[0];
            a1 += w * (float)xv[1];
            a2 += w * (float)xv[2];
            a3 += w * (float)xv[3];
        }
        __syncthreads();
    }
    f16* Zr = Z + (size_t)n * 1184;
    f16x4 o; o[0] = (f16)a0; o[1] = (f16)a1; o[2] = (f16)a2; o[3] = (f16)a3;
    *(f16x4*)(Zr + tid * 4) = o;
    if (tid < 16) *(f16x8*)(Zr + 1024 + tid * 8) = *(const f16x8*)(X + (size_t)n * 128 + tid * 8);
    if (tid >= 32 && tid < 40) {
        int hh = tid - 32;
        float s = 0.0f;
        for (int e = 0; e < d; ++e) s += sew[e * NH + hh];
        Zr[1152 + hh] = (f16)s;
    }
    if (tid >= 64 && tid < 88) Zr[1160 + (tid - 64)] = (f16)0.0f;
}

// ---------------- layers 2,3: logits + softmax + V aggregation + skip + ELU, fused ----
__global__ __launch_bounds__(256) void edge_node(const f16* __restrict__ QKVS,
                                                 const float* __restrict__ Sf,
                                                 const int* __restrict__ offs,
                                                 const int* __restrict__ srcCSR,
                                                 float* __restrict__ hout, f16* __restrict__ houth,
                                                 int Np, int C, int hc, float scale, int writeHout) {
    const int n = blockIdx.x;
    const int e0 = offs[n];
    int d = offs[n + 1] - e0;
    if (d > 256) d = 256;

    __shared__ __align__(16) f16 sq[4096];
    __shared__ float sew[256 * NH];
    __shared__ int sed[256];
    __shared__ float sred[512];
    const int tid = threadIdx.x;

    const f16x8* qg = (const f16x8*)(QKVS + (size_t)n * Np);
    const int qchunks = hc >> 3;
    for (int c = tid; c < qchunks; c += 256) ((f16x8*)sq)[c] = qg[c];
    for (int e = tid; e < d; e += 256) sed[e] = srcCSR[e0 + e];
    __syncthreads();

    {
        const int wv = tid >> 6, lane = tid & 63;
        const int cph = C >> 3;
        const int passes = (hc >> 9) ? (hc >> 9) : 1;
        for (int e = wv; e < d; e += 4) {
            const f16x8* kg = (const f16x8*)(QKVS + (size_t)sed[e] * Np + hc);
            for (int p = 0; p < passes; ++p) {
                const int ci = p * 64 + lane;
                f16x8 qv = ((const f16x8*)sq)[ci];
                f16x8 kv = kg[ci];
                float acc = 0.0f;
#pragma unroll
                for (int t = 0; t < 8; ++t) acc += (float)qv[t] * (float)kv[t];
                for (int o = cph >> 1; o > 0; o >>= 1) acc += __shfl_down(acc, o, cph);
                if ((lane & (cph - 1)) == 0) {
                    const int head = ci / cph;
                    sew[e * NH + head] = acc * scale;
                }
            }
        }
    }
    __syncthreads();

    if (tid < NH) {
        const int h = tid;
        float m = -3.0e38f;
        for (int e = 0; e < d; ++e) m = fmaxf(m, sew[e * NH + h]);
        float den = 0.0f;
        for (int e = 0; e < d; ++e) {
            float ex = __expf(sew[e * NH + h] - m);
            sew[e * NH + h] = ex;
            den += ex;
        }
        float inv = 1.0f / (fmaxf(den, 1e-16f) * (float)NH);
        for (int e = 0; e < d; ++e) sew[e * NH + h] *= inv;
    }
    __syncthreads();

    const int half = C >> 1;
    const int cp = tid & (half - 1);
    const int grp = tid / half;
    const int ngr = 256 / half;
    float a0 = 0.0f, a1 = 0.0f;
    for (int e = grp; e < d; e += ngr) {
        const unsigned int* vp = (const unsigned int*)(QKVS + (size_t)sed[e] * Np + 2 * hc);
#pragma unroll
        for (int h = 0; h < NH; ++h) {
            float w = sew[e * NH + h];
            f16x2 vv = __builtin_bit_cast(f16x2, vp[((h * C) >> 1) + cp]);
            a0 += w * (float)vv.x;
            a1 += w * (float)vv.y;
        }
    }
    if (ngr > 1) {
        sred[tid] = a0;
        sred[256 + tid] = a1;
        __syncthreads();
        if (grp == 0) {
            for (int g = 1; g < ngr; ++g) {
                a0 += sred[g * half + cp];
                a1 += sred[256 + g * half + cp];
            }
        }
    }
    if (grp == 0) {
        const int c = cp * 2;
        const float* Sp = Sf + (size_t)n * C;
        float o0 = a0 + Sp[c];
        float o1 = a1 + Sp[c + 1];
        o0 = o0 > 0.0f ? o0 : (__expf(o0) - 1.0f);
        o1 = o1 > 0.0f ? o1 : (__expf(o1) - 1.0f);
        if (writeHout) {
            hout[(size_t)n * C + c] = o0;
            hout[(size_t)n * C + c + 1] = o1;
        }
        houth[(size_t)n * C + c] = (f16)o0;
        houth[(size_t)n * C + c + 1] = (f16)o1;
    }
}

// ---------------- fused pooling + final FC ----------------
__global__ __launch_bounds__(256) void pool_graph(const float* __restrict__ h,
                                                  const float* __restrict__ gw, const float* __restrict__ gb,
                                                  const float* __restrict__ fcw, const float* __restrict__ fcb,
                                                  const int* __restrict__ goffs,
                                                  float* __restrict__ gbuf, float* __restrict__ out) {
    const int g = blockIdx.x;
    const int s = goffs[g], e = goffs[g + 1];
    const int tid = threadIdx.x;
    const int wv = tid >> 6, lane = tid & 63;

    __shared__ float red[256];
    __shared__ float pl[64];
    __shared__ float sden;

    if (e == s) {
        if (tid < 10) out[g * 10 + tid] = fcb[tid];
        return;
    }

    const float gwl = gw[lane];
    for (int n = s + wv; n < e; n += 4) {
        float acc = h[(size_t)n * 64 + lane] * gwl;
#pragma unroll
        for (int o = 32; o > 0; o >>= 1) acc += __shfl_down(acc, o, 64);
        if (lane == 0) gbuf[n] = acc + gb[0];
    }
    __syncthreads();

    float m = -3.0e38f;
    for (int n = s + tid; n < e; n += 256) m = fmaxf(m, gbuf[n]);
    red[tid] = m;
    __syncthreads();
    for (int o = 128; o > 0; o >>= 1) {
        if (tid < o) red[tid] = fmaxf(red[tid], red[tid + o]);
        __syncthreads();
    }
    m = red[0];
    __syncthreads();

    float sum = 0.0f;
    for (int n = s + tid; n < e; n += 256) {
        float ex = __expf(gbuf[n] - m);
        gbuf[n] = ex;
        sum += ex;
    }
    red[tid] = sum;
    __syncthreads();
    for (int o = 128; o > 0; o >>= 1) {
        if (tid < o) red[tid] += red[tid + o];
        __syncthreads();
    }
    if (tid == 0) sden = 1.0f / fmaxf(red[0], 1e-16f);
    __syncthreads();

    float acc = 0.0f;
    for (int n = s + wv; n < e; n += 4) acc += gbuf[n] * h[(size_t)n * 64 + lane];
    red[tid] = acc;
    __syncthreads();
    if (wv == 0) pl[lane] = (red[lane] + red[64 + lane] + red[128 + lane] + red[192 + lane]) * sden;
    __syncthreads();

    if (tid < 10) {
        float o = fcb[tid];
#pragma unroll
        for (int c = 0; c < 64; ++c) o += pl[c] * fcw[c * 10 + tid];
        out[g * 10 + tid] = o;
    }
}

// ---------------- host ----------------
extern "C" void kernel_launch(void* const* d_in, const int* in_sizes, int n_in,
                              void* d_out, int out_size, void* d_ws, size_t ws_size,
                              hipStream_t stream) {
    const float* x   = (const float*)d_in[0];
    const int* ei    = (const int*)d_in[1];
    const int* src   = ei;
    const int* dst   = ei + NE;
    const int* batch = (const int*)d_in[2];

    struct LayerW { int fin, C, hc; const float *qw,*qb,*kw,*kb,*vw,*vb,*sw,*sb; };
    LayerW LW[3];
    const int fins[3] = {128, 512, 256};
    const int Cs[3]   = {512, 256, 64};
    for (int l = 0; l < 3; ++l) {
        int b = 3 + 8 * l;
        LW[l].fin = fins[l]; LW[l].C = Cs[l]; LW[l].hc = Cs[l] * NH;
        LW[l].qw = (const float*)d_in[b + 0]; LW[l].qb = (const float*)d_in[b + 1];
        LW[l].kw = (const float*)d_in[b + 2]; LW[l].kb = (const float*)d_in[b + 3];
        LW[l].vw = (const float*)d_in[b + 4]; LW[l].vb = (const float*)d_in[b + 5];
        LW[l].sw = (const float*)d_in[b + 6]; LW[l].sb = (const float*)d_in[b + 7];
    }
    const float* gate_w = (const float*)d_in[27];
    const float* gate_b = (const float*)d_in[28];
    const float* fc_w   = (const float*)d_in[29];
    const float* fc_b   = (const float*)d_in[30];

    size_t off = 0;
    char* ws = (char*)d_ws;
    auto alloc = [&](size_t bytes) -> void* {
        void* p = ws + off;
        off = (off + bytes + 255) & ~(size_t)255;
        return p;
    };
    f16* BtL2   = (f16*)alloc((size_t)6400 * 512 * sizeof(f16));
    f16* BtL3   = (f16*)alloc((size_t)1664 * 256 * sizeof(f16));
    f16* BtZ    = (f16*)alloc((size_t)512 * 1184 * sizeof(f16));
    float* biasL2 = (float*)alloc(6400 * sizeof(float));
    float* biasL3 = (float*)alloc(1664 * sizeof(float));
    float* biasZ  = (float*)alloc(512 * sizeof(float));
    f16* QKbuf  = (f16*)alloc((size_t)NN * 6400 * sizeof(f16));
    f16* Zbuf   = (f16*)alloc((size_t)NN * 1184 * sizeof(f16));
    float* Sf   = (float*)alloc((size_t)NN * 256 * sizeof(float));
    f16* xh     = (f16*)alloc((size_t)NN * 128 * sizeof(f16));
    f16* houth  = (f16*)alloc((size_t)NN * 512 * sizeof(f16));
    float* hf   = (float*)alloc((size_t)NN * 64 * sizeof(float));
    f16* qw16   = (f16*)alloc((size_t)128 * 4096 * sizeof(f16));
    f16* kw16   = (f16*)alloc((size_t)128 * 4096 * sizeof(f16));
    f16* BtY    = (f16*)alloc((size_t)1152 * 128 * sizeof(f16));
    float* zbias = (float*)alloc(512 * sizeof(float));
    float* biasY = (float*)alloc(1152 * sizeof(float));
    int* deg    = (int*)alloc(NN * sizeof(int));
    int* offs   = (int*)alloc((NN + 1) * sizeof(int));
    int* cursor = (int*)alloc(NN * sizeof(int));
    int* srcCSR = (int*)alloc(NE * sizeof(int));
    int* goffs  = (int*)alloc((NG + 1) * sizeof(int));
    float* gbuf = (float*)alloc(NN * sizeof(float));
    if (off > ws_size) return;

    megaprep<<<MB_TOTAL, 256, 0, stream>>>(
        x, xh, LW[0].qw, qw16, LW[0].kw, kw16,
        LW[0].qb, LW[0].kb, LW[0].vw, LW[0].sw, LW[0].vb, LW[0].sb,
        LW[1].qw, LW[1].qb, LW[1].kw, LW[1].kb, LW[1].vw, LW[1].vb, LW[1].sw, LW[1].sb,
        LW[2].qw, LW[2].qb, LW[2].kw, LW[2].kb, LW[2].vw, LW[2].vb, LW[2].sw, LW[2].sb,
        BtL2, biasL2, BtL3, biasL3, BtZ, biasZ, BtY, biasY, zbias, deg);

    hist_kernel<<<(NE + 255) / 256, 256, 0, stream>>>(dst, deg, NE);
    scan_goffs<<<2, 1024, 0, stream>>>(deg, offs, cursor, batch, goffs);
    scatter_kernel<<<(NE + 255) / 256, 256, 0, stream>>>(src, dst, cursor, srcCSR, NE);
    sort_csr<<<(NN + 255) / 256, 256, 0, stream>>>(offs, srcCSR);

    const int grid_m = 80;   // mult of 8: XCD-stable across y-passes

    // ---- layer 1: Y-trick alpha + fused softmax + Z aggregation + Z-GEMM ----
    {
        const int fin = 128, hc = 4096, NtotY = 1152;
        const float scale = 1.0f / sqrtf(512.0f);
        dim3 gm(1, 1, 8);
        gemm128<<<gm, 256, 0, stream>>>(kw16, hc, 512, qw16, hc, 512, zbias,
                                        BtY, fin, fin * fin, nullptr, fin, fin, 512, 0, 0, 0);
        dim3 gy(grid_m, NtotY / 128);
        gemm128<<<gy, 256, 0, stream>>>(xh, fin, 0, BtY, fin, 0, biasY,
                                        QKbuf, NtotY, 0, nullptr, NN, NtotY, fin, 0, 0, 0);
        alpha_zagg<<<NN, 256, 0, stream>>>(QKbuf, xh, offs, srcCSR, Zbuf, NtotY, scale);
        dim3 gz(grid_m, 4);
        gemm128<<<gz, 256, 0, stream>>>(Zbuf, 1184, 0, BtZ, 1184, 0, biasZ,
                                        houth, 512, 0, nullptr, NN, 512, 1184, 0, 0, 1);
    }
    // ---- layers 2,3: fused Q|K|V|S GEMM + fused edge/node kernel ----
    const f16* Acur = houth;
    for (int l = 1; l < 3; ++l) {
        const int K = LW[l].fin, C = LW[l].C, hc = LW[l].hc;
        const float scale = 1.0f / sqrtf((float)C);
        const int Np = (3 * hc + C + 127) & ~127;   // L2: 6400, L3: 1664
        f16* Bt = (l == 1) ? BtL2 : BtL3;
        float* bias = (l == 1) ? biasL2 : biasL3;
        dim3 gq(grid_m, Np / 128);
        gemm128<<<gq, 256, 0, stream>>>(Acur, K, 0, Bt, K, 0, bias,
                                        QKbuf, Np, 0, Sf, NN, Np, K, 3 * hc, C, 0);
        edge_node<<<NN, 256, 0, stream>>>(QKbuf, Sf, offs, srcCSR, hf, houth,
                                          Np, C, hc, scale, l == 2 ? 1 : 0);
        Acur = houth;
    }

    pool_graph<<<NG, 256, 0, stream>>>(hf, gate_w, gate_b, fc_w, fc_b, goffs, gbuf, (float*)d_out);
}